// Round 2
// baseline (119.159 us; speedup 1.0000x reference)
//
#include <hip/hip_runtime.h>

#define BB 2
#define NN 1000
#define NC 81
#define CC 80
#define SCORE_THRESH 0.05f
#define NMS_THRESH 0.5f
#define DET_PER_IMG 100

// Kernel A: per-row softmax over 81 classes; write scores (dropping background
// column 0) transposed to [B, C, N] so each NMS task reads contiguously.
__global__ void softmax_scores_kernel(const float* __restrict__ logits,
                                      float* __restrict__ sc) {
    int r = blockIdx.x * blockDim.x + threadIdx.x;
    if (r >= BB * NN) return;
    const float* z = logits + (size_t)r * NC;
    float mx = z[0];
    for (int k = 1; k < NC; k++) mx = fmaxf(mx, z[k]);
    float sum = 0.f;
    for (int k = 0; k < NC; k++) sum += expf(z[k] - mx);
    float inv = 1.f / sum;
    int b = r / NN, n = r % NN;
    for (int c = 0; c < CC; c++) {
        sc[((size_t)(b * CC + c)) * NN + n] = expf(z[c + 1] - mx) * inv;
    }
}

// Kernel B: one block per (image, class) task.
__global__ __launch_bounds__(256) void nms_task_kernel(
    const float* __restrict__ sc,      // [B*C, N] scores
    const float* __restrict__ boxreg,  // [B*N, C*4]
    const float* __restrict__ props,   // [B*N, 4]
    float* __restrict__ out) {         // [B*C, N, 5], pre-zeroed
    __shared__ float s_sc[NN];
    __shared__ int   s_vn[NN];    // valid item -> proposal index (unsorted)
    __shared__ int   s_rank[NN];  // valid item -> global sorted rank (unsorted)
    __shared__ int   s_sn[NN];    // sorted pos -> proposal index
    __shared__ int   s_sr[NN];    // sorted pos -> global rank
    __shared__ float s_x1[NN], s_y1[NN], s_x2[NN], s_y2[NN], s_ar[NN];
    __shared__ int   s_supp[NN];
    __shared__ int   s_kf[NN];    // kept-order (1-based) or 0
    __shared__ int   s_V;

    const int t = blockIdx.x;
    const int b = t / CC, c = t % CC;
    const int tid = threadIdx.x;

    // 1. load this task's 1000 scores
    const float* scb = sc + (size_t)t * NN;
    for (int n = tid; n < NN; n += 256) s_sc[n] = scb[n];
    if (tid == 0) s_V = 0;
    __syncthreads();

    // 2. compact valid set (score > thresh)
    for (int n = tid; n < NN; n += 256) {
        if (s_sc[n] > SCORE_THRESH) {
            int i = atomicAdd(&s_V, 1);
            s_vn[i] = n;
        }
    }
    __syncthreads();
    const int V = s_V;

    // 3. global rank of each valid item among all 1000 (stable argsort position)
    for (int i = tid; i < V; i += 256) s_rank[i] = 0;
    __syncthreads();
    for (int n = tid; n < NN; n += 256) {
        float sn = s_sc[n];
        for (int i = 0; i < V; i++) {
            int nv = s_vn[i];
            float sv = s_sc[nv];
            if (sn > sv || (sn == sv && n < nv)) atomicAdd(&s_rank[i], 1);
        }
    }
    __syncthreads();

    // 4. order valid items by rank (ranks are distinct)
    for (int i = tid; i < V; i += 256) {
        int r = s_rank[i];
        int p = 0;
        for (int u = 0; u < V; u++) p += (s_rank[u] < r) ? 1 : 0;
        s_sn[p] = s_vn[i];
        s_sr[p] = r;
    }
    __syncthreads();

    // 5. decode boxes only for the valid items
    for (int p = tid; p < V; p += 256) {
        int n = s_sn[p];
        int row = b * NN + n;
        float p0 = props[row * 4 + 0], p1 = props[row * 4 + 1];
        float p2 = props[row * 4 + 2], p3 = props[row * 4 + 3];
        float px = (p0 + p2) * 0.5f, py = (p1 + p3) * 0.5f;
        float pw = p2 - p0, ph = p3 - p1;
        const float* rg = boxreg + (size_t)row * (CC * 4) + c * 4;
        float gx = rg[0] * pw + px;
        float gy = rg[1] * ph + py;
        float gw = pw * expf(rg[2]);
        float gh = ph * expf(rg[3]);
        float x1 = gx - gw * 0.5f, y1 = gy - gh * 0.5f;
        float x2 = gx + gw * 0.5f, y2 = gy + gh * 0.5f;
        s_x1[p] = x1; s_y1[p] = y1; s_x2[p] = x2; s_y2[p] = y2;
        s_ar[p] = (x2 - x1) * (y2 - y1);   // match reference's area expression
        s_supp[p] = 0;
        s_kf[p] = 0;
    }
    __syncthreads();

    // 6. greedy NMS over the V sorted items (serial over i, parallel over j).
    // Note: cap (<=100) applies only to output, not to suppression — matches
    // the reference scan where keep is computed uncapped.
    int kc = 0;
    for (int i = 0; i < V; i++) {
        if (s_supp[i]) continue;      // uniform branch: all threads read same LDS
        kc++;
        if (tid == 0) s_kf[i] = kc;
        float x1i = s_x1[i], y1i = s_y1[i], x2i = s_x2[i], y2i = s_y2[i];
        float ai = s_ar[i];
        for (int j = i + 1 + tid; j < V; j += 256) {
            float xx = fmaxf(x1i, s_x1[j]);
            float yy = fmaxf(y1i, s_y1[j]);
            float w = fminf(x2i, s_x2[j]) - xx;
            float h = fminf(y2i, s_y2[j]) - yy;
            w = fmaxf(w, 0.f);
            h = fmaxf(h, 0.f);
            float inter = w * h;
            float iou = inter / (ai + s_ar[j] - inter);
            if (iou > NMS_THRESH) s_supp[j] = 1;
        }
        __syncthreads();
    }
    __syncthreads();

    // 7. scatter kept detections to their global-rank positions
    for (int p = tid; p < V; p += 256) {
        int kf = s_kf[p];
        if (kf > 0 && kf <= DET_PER_IMG) {
            size_t o = ((size_t)t * NN + (size_t)s_sr[p]) * 5;
            out[o + 0] = s_x1[p];
            out[o + 1] = s_y1[p];
            out[o + 2] = s_x2[p];
            out[o + 3] = s_y2[p];
            out[o + 4] = s_sc[s_sn[p]];
        }
    }
}

extern "C" void kernel_launch(void* const* d_in, const int* in_sizes, int n_in,
                              void* d_out, int out_size, void* d_ws, size_t ws_size,
                              hipStream_t stream) {
    const float* logits = (const float*)d_in[0];   // [B*N, 81]
    const float* boxreg = (const float*)d_in[1];   // [B*N, C*4]
    const float* props  = (const float*)d_in[2];   // [B, N, 4]
    float* out = (float*)d_out;                    // [B, C, N, 5]
    float* sc  = (float*)d_ws;                     // [B, C, N] scores (640 KB)

    hipMemsetAsync(d_out, 0, (size_t)out_size * sizeof(float), stream);
    softmax_scores_kernel<<<(BB * NN + 255) / 256, 256, 0, stream>>>(logits, sc);
    nms_task_kernel<<<BB * CC, 256, 0, stream>>>(sc, boxreg, props, out);
}

// Round 4
// 99.478 us; speedup vs baseline: 1.1978x; 1.1978x over previous
//
#include <hip/hip_runtime.h>

#define BB 2
#define NN 1000
#define NC 81
#define CC 80
#define SCORE_THRESH 0.05f
#define NMS_THRESH 0.5f
#define DET_PER_IMG 100

// Kernel A: per-row softmax statistics (max, 1/sum) over the 81 logits.
// Only 16 KB of intermediate instead of a 640 KB transposed score matrix.
__global__ void row_stats_kernel(const float* __restrict__ logits,
                                 float* __restrict__ mx_out,
                                 float* __restrict__ inv_out) {
    int r = blockIdx.x * blockDim.x + threadIdx.x;
    if (r >= BB * NN) return;
    const float* z = logits + (size_t)r * NC;
    float mx = z[0];
    #pragma unroll
    for (int k = 1; k < NC; k++) mx = fmaxf(mx, z[k]);
    float sum = 0.f;
    #pragma unroll
    for (int k = 0; k < NC; k++) sum += expf(z[k] - mx);
    mx_out[r] = mx;
    inv_out[r] = 1.f / sum;   // same numeric path as the passing round-2 run
}

// Kernel B: one block per (image, class) task. Zeroes its own output slice
// (replaces the hipMemsetAsync dispatch), reconstructs scores from row stats,
// then compact -> rank -> sort -> decode -> greedy NMS -> scatter.
__global__ __launch_bounds__(256) void nms_task_kernel(
    const float* __restrict__ logits,  // [B*N, 81]
    const float* __restrict__ mx_in,   // [B*N]
    const float* __restrict__ inv_in,  // [B*N]
    const float* __restrict__ boxreg,  // [B*N, C*4]
    const float* __restrict__ props,   // [B*N, 4]
    float* __restrict__ out) {         // [B*C, N, 5]
    __shared__ float s_sc[NN];
    __shared__ float s_vs[NN];    // valid item -> score (cache: avoids dependent LDS reads)
    __shared__ int   s_vn[NN];    // valid item -> proposal index (unsorted)
    __shared__ int   s_rank[NN];  // valid item -> global sorted rank (unsorted)
    __shared__ int   s_sn[NN];    // sorted pos -> proposal index
    __shared__ float s_ss[NN];    // sorted pos -> score
    __shared__ int   s_sr[NN];    // sorted pos -> global rank
    __shared__ float s_x1[NN], s_y1[NN], s_x2[NN], s_y2[NN], s_ar[NN];
    __shared__ int   s_supp[NN];
    __shared__ int   s_kf[NN];    // kept-order (1-based) or 0
    __shared__ int   s_V;

    const int t = blockIdx.x;
    const int b = t / CC, c = t % CC;
    const int tid = threadIdx.x;

    // 0. zero this task's output slice (1000*5 floats = 1250 float4, 16B-aligned)
    float4* outv = (float4*)(out + (size_t)t * NN * 5);
    #pragma unroll
    for (int k = tid; k < NN * 5 / 4; k += 256)
        outv[k] = make_float4(0.f, 0.f, 0.f, 0.f);

    // 1. reconstruct this task's 1000 scores from row stats
    const int rowbase = b * NN;
    for (int n = tid; n < NN; n += 256) {
        int r = rowbase + n;
        float z = logits[(size_t)r * NC + (c + 1)];
        s_sc[n] = expf(z - mx_in[r]) * inv_in[r];
    }
    if (tid == 0) s_V = 0;
    __syncthreads();

    // 2. compact valid set (score > thresh), caching scores
    for (int n = tid; n < NN; n += 256) {
        float s = s_sc[n];
        if (s > SCORE_THRESH) {
            int i = atomicAdd(&s_V, 1);
            s_vn[i] = n;
            s_vs[i] = s;
        }
    }
    __syncthreads();
    const int V = s_V;

    // 3. global rank of each valid item among all 1000 (stable argsort position)
    for (int i = tid; i < V; i += 256) s_rank[i] = 0;
    __syncthreads();
    for (int n = tid; n < NN; n += 256) {
        float sn = s_sc[n];
        for (int i = 0; i < V; i++) {
            float sv = s_vs[i];
            if (sn > sv || (sn == sv && n < s_vn[i])) atomicAdd(&s_rank[i], 1);
        }
    }
    __syncthreads();

    // 4. order valid items by rank (ranks are distinct via stable tiebreak)
    for (int i = tid; i < V; i += 256) {
        int r = s_rank[i];
        int p = 0;
        for (int u = 0; u < V; u++) p += (s_rank[u] < r) ? 1 : 0;
        s_sn[p] = s_vn[i];
        s_ss[p] = s_vs[i];
        s_sr[p] = r;
    }
    __syncthreads();

    // 5. decode boxes only for the valid items
    for (int p = tid; p < V; p += 256) {
        int n = s_sn[p];
        int row = rowbase + n;
        float p0 = props[row * 4 + 0], p1 = props[row * 4 + 1];
        float p2 = props[row * 4 + 2], p3 = props[row * 4 + 3];
        float px = (p0 + p2) * 0.5f, py = (p1 + p3) * 0.5f;
        float pw = p2 - p0, ph = p3 - p1;
        const float* rg = boxreg + (size_t)row * (CC * 4) + c * 4;
        float gx = rg[0] * pw + px;
        float gy = rg[1] * ph + py;
        float gw = pw * expf(rg[2]);
        float gh = ph * expf(rg[3]);
        float x1 = gx - gw * 0.5f, y1 = gy - gh * 0.5f;
        float x2 = gx + gw * 0.5f, y2 = gy + gh * 0.5f;
        s_x1[p] = x1; s_y1[p] = y1; s_x2[p] = x2; s_y2[p] = y2;
        s_ar[p] = (x2 - x1) * (y2 - y1);
        s_supp[p] = 0;
        s_kf[p] = 0;
    }
    __syncthreads();

    // 6. greedy NMS (serial over kept i, parallel over j). Cap applies only to
    // output, not suppression — matches the reference's uncapped scan.
    int kc = 0;
    for (int i = 0; i < V; i++) {
        if (s_supp[i]) continue;   // uniform: all threads read same pre-barrier LDS
        kc++;
        if (tid == 0) s_kf[i] = kc;
        float x1i = s_x1[i], y1i = s_y1[i], x2i = s_x2[i], y2i = s_y2[i];
        float ai = s_ar[i];
        for (int j = i + 1 + tid; j < V; j += 256) {
            float xx = fmaxf(x1i, s_x1[j]);
            float yy = fmaxf(y1i, s_y1[j]);
            float w = fmaxf(fminf(x2i, s_x2[j]) - xx, 0.f);
            float h = fmaxf(fminf(y2i, s_y2[j]) - yy, 0.f);
            float inter = w * h;
            float iou = inter / (ai + s_ar[j] - inter);
            if (iou > NMS_THRESH) s_supp[j] = 1;
        }
        __syncthreads();
    }
    __syncthreads();

    // 7. scatter kept detections to their global-rank positions
    for (int p = tid; p < V; p += 256) {
        int kf = s_kf[p];
        if (kf > 0 && kf <= DET_PER_IMG) {
            size_t o = ((size_t)t * NN + (size_t)s_sr[p]) * 5;
            out[o + 0] = s_x1[p];
            out[o + 1] = s_y1[p];
            out[o + 2] = s_x2[p];
            out[o + 3] = s_y2[p];
            out[o + 4] = s_ss[p];
        }
    }
}

extern "C" void kernel_launch(void* const* d_in, const int* in_sizes, int n_in,
                              void* d_out, int out_size, void* d_ws, size_t ws_size,
                              hipStream_t stream) {
    const float* logits = (const float*)d_in[0];   // [B*N, 81]
    const float* boxreg = (const float*)d_in[1];   // [B*N, C*4]
    const float* props  = (const float*)d_in[2];   // [B, N, 4]
    float* out = (float*)d_out;                    // [B, C, N, 5]
    float* mx  = (float*)d_ws;                     // [B*N]
    float* inv = mx + BB * NN;                     // [B*N]

    row_stats_kernel<<<(BB * NN + 255) / 256, 256, 0, stream>>>(logits, mx, inv);
    nms_task_kernel<<<BB * CC, 256, 0, stream>>>(logits, mx, inv, boxreg, props, out);
}